// Round 11
// baseline (910.425 us; speedup 1.0000x reference)
//
#include <hip/hip_runtime.h>
#include <hip/hip_bf16.h>
#include <stdint.h>

// ---------------------------------------------------------------------------
// AdaptiveAngleConv: 5 angles of (bilinear deform-sample -> 3x3 conv)
// x: (2,256,64,64) f32, weight: (256,256,3,3) f32
// out: 5 x (2,256,190,190) f32 concatenated
// Conv v8: block 256px x 128oc, 4 waves, wave 128x64 via 4x2 frags of
// mfma_f32_32x32x16_bf16, BK=32 tap-inner, plain dbuf loop (round-1/9
// structure), 48KB LDS -> 2 blocks/CU. 12 ds_read feed 16 MFMA per step
// (0.75x LDS + global traffic per FLOP vs round 10). Conflict-free
// slot-XOR layout (involution on stage source and frag read).
// ---------------------------------------------------------------------------

#define S2F 1.41421356237309515f

__constant__ float c_ox[5][9] = {
  {0.f,0.f,0.f,0.f,0.f,0.f,0.f,0.f,0.f},
  {1.f-S2F, 1.f-S2F*0.5f, 1.f, -S2F*0.5f, 0.f, S2F*0.5f, -1.f, S2F*0.5f-1.f, S2F-1.f},
  {0.f,1.f,2.f,-1.f,0.f,1.f,-2.f,-1.f,0.f},
  {1.f, 1.f+S2F*0.5f, 1.f+S2F, -S2F*0.5f, 0.f, S2F*0.5f, -1.f-S2F, -1.f-S2F*0.5f, -1.f},
  {2.f,2.f,2.f,0.f,0.f,0.f,-2.f,-2.f,-2.f}
};
__constant__ float c_oy[5][9] = {
  {0.f,0.f,0.f,0.f,0.f,0.f,0.f,0.f,0.f},
  {1.f, S2F*0.5f, S2F-1.f, 1.f-S2F*0.5f, 0.f, S2F*0.5f-1.f, 1.f-S2F, -S2F*0.5f, -1.f},
  {2.f,1.f,0.f,1.f,0.f,-1.f,0.f,-1.f,-2.f},
  {1.f+S2F, S2F*0.5f, -1.f, 1.f+S2F*0.5f, 0.f, -1.f-S2F*0.5f, 1.f, -S2F*0.5f, 1.f+S2F},
  {2.f,0.f,-2.f,2.f,0.f,-2.f,2.f,0.f,-2.f}
};

typedef __bf16 bf16x8_t __attribute__((ext_vector_type(8)));
typedef float f32x4_t __attribute__((ext_vector_type(4)));
typedef float f32x16_t __attribute__((ext_vector_type(16)));

typedef const __attribute__((address_space(1))) void* as1cp;
typedef __attribute__((address_space(3))) void* as3p;

__device__ __forceinline__ void gload16(const void* g, void* l) {
  __builtin_amdgcn_global_load_lds((as1cp)g, (as3p)l, 16, 0, 0);
}

// x NCHW (2,256,64,64) -> xT NHWC (2,64,64,256) f32
__global__ void k_transpose(const float* __restrict__ x, float* __restrict__ xT) {
  const int v = blockIdx.x, u = blockIdx.y, b = blockIdx.z;
  const int ic = threadIdx.x;
  xT[(((b*64 + u)*64 + v)*256) + ic] =
      x[(((b*256 + ic)*64 + u)*64) + v];
}

// weight OIHW (256,256,3,3) f32 -> wb (9,256,256)=[t][oc][ic] bf16
__global__ void k_wconv(const float* __restrict__ w, __hip_bfloat16* __restrict__ wb) {
  const int tid = blockIdx.x*256 + threadIdx.x;   // < 9*256*256
  const int t = tid >> 16;
  const int rem = tid & 65535;
  const int oc = rem >> 8;
  const int ic = rem & 255;
  wb[tid] = __float2bfloat16(w[(oc*256 + ic)*9 + t]);
}

// bilinear deform-sample -> xo bf16 NHWC [(a)][b][192][192][256]
__global__ void k_sample(const float* __restrict__ xT,
                         __hip_bfloat16* __restrict__ xo, int a0)
{
  const int aidx = a0 + blockIdx.z;
  __hip_bfloat16* xoa = xo + (size_t)blockIdx.z * (2ull*192*192*256);

  const int tid = threadIdx.x;           // 256
  const int ic = (tid & 63) * 4;
  const int j = blockIdx.x*4 + (tid >> 6);
  const int i = blockIdx.y;

  const int a = i / 3, r = i - 3*a;
  const int bc = j / 3, s = j - 3*bc;
  const int n = r*3 + s;
  const float px = (float)(a + r) + c_ox[aidx][n];
  const float py = (float)(bc + s) + c_oy[aidx][n];
  const float fx = floorf(px), fy = floorf(py);
  const float pxc = fminf(fmaxf(px, 0.f), 65.f);
  const float pyc = fminf(fmaxf(py, 0.f), 65.f);
  const int qlx = (int)fminf(fmaxf(fx,      0.f), 65.f);
  const int qrx = (int)fminf(fmaxf(fx + 1.f, 0.f), 65.f);
  const int qly = (int)fminf(fmaxf(fy,      0.f), 65.f);
  const int qry = (int)fminf(fmaxf(fy + 1.f, 0.f), 65.f);
  const float wlx = 1.f + (float)qlx - pxc;
  const float wrx = 1.f - (float)qrx + pxc;
  const float wly = 1.f + (float)qly - pyc;
  const float wry = 1.f - (float)qry + pyc;
  const float glt = wlx*wly, grb = wrx*wry, glb = wlx*wry, grt = wrx*wly;

  const bool inxl = (qlx >= 1) && (qlx <= 64);
  const bool inxr = (qrx >= 1) && (qrx <= 64);
  const bool inyl = (qly >= 1) && (qly <= 64);
  const bool inyr = (qry >= 1) && (qry <= 64);

  const f32x4_t zero = (f32x4_t){0.f,0.f,0.f,0.f};
  #pragma unroll
  for (int b = 0; b < 2; ++b) {
    const float* xb = xT + (size_t)b * (64*64*256);
    f32x4_t vlt = (inxl && inyl) ? *(const f32x4_t*)&xb[((qlx-1)*64 + (qly-1))*256 + ic] : zero;
    f32x4_t vrb = (inxr && inyr) ? *(const f32x4_t*)&xb[((qrx-1)*64 + (qry-1))*256 + ic] : zero;
    f32x4_t vlb = (inxl && inyr) ? *(const f32x4_t*)&xb[((qlx-1)*64 + (qry-1))*256 + ic] : zero;
    f32x4_t vrt = (inxr && inyl) ? *(const f32x4_t*)&xb[((qrx-1)*64 + (qly-1))*256 + ic] : zero;
    ushort4 pk;
    float v0 = glt*vlt[0] + grb*vrb[0] + glb*vlb[0] + grt*vrt[0];
    float v1 = glt*vlt[1] + grb*vrb[1] + glb*vlb[1] + grt*vrt[1];
    float v2 = glt*vlt[2] + grb*vrb[2] + glb*vlb[2] + grt*vrt[2];
    float v3 = glt*vlt[3] + grb*vrb[3] + glb*vlb[3] + grt*vrt[3];
    pk.x = __hip_bfloat16_raw(__float2bfloat16(v0)).x;
    pk.y = __hip_bfloat16_raw(__float2bfloat16(v1)).x;
    pk.z = __hip_bfloat16_raw(__float2bfloat16(v2)).x;
    pk.w = __hip_bfloat16_raw(__float2bfloat16(v3)).x;
    *(ushort4*)&xoa[(((size_t)b*192 + i)*192 + j)*256 + ic] = pk;
  }
}

// ---------------------------------------------------------------------------
// conv v8: implicit GEMM. grid (6, 48, nZ): x = octile(2) x coltile(3),
// y = row-quad (i0 = 4y), z = ab. Block 256px x 128oc, 4 waves (2Mx2N),
// wave 128px x 64oc = 4x2 frags of 32x32x16. K: kk=0..71, tap-inner
// (icg = kk/9 of 32 ic, tap = kk%9). LDS: A dbuf 2x16KB @0, B dbuf 2x8KB
// @32768 (48KB); epilogue reuses as f32[64][132] per pass.
// ---------------------------------------------------------------------------
__global__ __launch_bounds__(256, 2) void k_conv8(
    const __hip_bfloat16* __restrict__ xo,   // [z][192][192][256] bf16
    const __hip_bfloat16* __restrict__ wb,   // [9][256][256] bf16 (t,oc,ic)
    float* __restrict__ out)                 // + z*9241600 : [256][190][190]
{
  __shared__ __align__(16) char smem[49152];
  const int tid = threadIdx.x;
  const int nt = blockIdx.x & 1;
  const int ct = blockIdx.x >> 1;
  const int i0 = blockIdx.y * 4;
  const int z  = blockIdx.z;
  const int oc0 = nt * 128;
  const int j0 = ct * 64;

  const int w = tid >> 6, l = tid & 63;
  const int l31 = l & 31, hi = l >> 5;
  const int wm = w >> 1, wn = w & 1;

  const char* xob = (const char*)xo + (size_t)z * 18874368u;
  const char* wbc = (const char*)wb;

  // staging constants: chunk c = p*256 + tid -> px = p*64 + (tid>>2) (A),
  // ocr = p*64 + (tid>>2) (B); phys slot tid&3 holds ic-slot (tid&3)^((tid>>2)&3)
  const int aCol = j0 + (tid >> 2);
  const int sOff = ((tid & 3) ^ ((tid >> 2) & 3)) * 16;   // involution
  const int bOc0 = (oc0 + (tid >> 2)) * 512;              // +32768 for p=1
  char* const dA = smem + w*1024;
  char* const dB = smem + 32768 + w*1024;

  auto stage = [&](int kk, int cur) {
    const int icg = kk / 9;                 // ic group of 32 (tap-inner)
    const int t   = kk - icg*9;
    const int ki = (t >= 6) ? 2 : ((t >= 3) ? 1 : 0);
    const int kj = t - ki*3;
    const int icoff = icg*64 + sOff;
    char* Ad = dA + cur*16384;
    char* Bd = dB + cur*8192;
    int j = aCol + kj; if (j > 191) j = 191;       // garbage cols never stored
    #pragma unroll
    for (int p = 0; p < 4; ++p) {
      int i = i0 + p + ki; if (i > 191) i = 191;   // garbage rows never stored
      gload16(xob + (size_t)(((i*192 + j) << 9) + icoff), Ad + p*4096);
    }
    const char* bs = wbc + t*131072 + icoff;
    gload16(bs + bOc0,         Bd);
    gload16(bs + bOc0 + 32768, Bd + 4096);
  };

  f32x16_t acc[4][2];
  #pragma unroll
  for (int mf = 0; mf < 4; ++mf)
    #pragma unroll
    for (int nf = 0; nf < 2; ++nf)
      #pragma unroll
      for (int v = 0; v < 16; ++v)
        acc[mf][nf][v] = 0.f;

  // frag read row bases ([row][4 slots of 16B], row stride 64B)
  const int rofA = (wm*128 + l31) * 64;
  const int rofB = (wn*64  + l31) * 64;

  auto compute = [&](int cur) {
    const char* Ab = smem + cur*16384;
    const char* Bb = smem + 32768 + cur*8192;
    #pragma unroll
    for (int ks = 0; ks < 2; ++ks) {
      const int sl = (((ks*2 + hi) ^ (l31 & 3)) * 16);
      const bf16x8_t b0 = *(const bf16x8_t*)(Bb + rofB + sl);
      const bf16x8_t b1 = *(const bf16x8_t*)(Bb + rofB + 2048 + sl);
      #pragma unroll
      for (int mf = 0; mf < 4; ++mf) {
        const bf16x8_t a = *(const bf16x8_t*)(Ab + rofA + mf*2048 + sl);
        acc[mf][0] = __builtin_amdgcn_mfma_f32_32x32x16_bf16(a, b0, acc[mf][0], 0, 0, 0);
        acc[mf][1] = __builtin_amdgcn_mfma_f32_32x32x16_bf16(a, b1, acc[mf][1], 0, 0, 0);
      }
    }
  };

  stage(0, 0);
  __syncthreads();
  for (int kk = 0; kk < 72; ++kk) {
    const int cur = kk & 1;
    if (kk < 71) stage(kk + 1, cur ^ 1);
    compute(cur);
    __syncthreads();
  }

  // --- epilogue: 4 passes through eps f32[64 oc][132 px] (33.8KB) ---
  // C/D 32x32 mapping (round-6/7-verified): oc = l31, px = (v&3)+8*(v>>2)+4*hi
  float* eps = (float*)smem;
  float* outb = out + (size_t)z * 9241600u;
  const int ocr = tid >> 2, q = tid & 3;

  #pragma unroll
  for (int pass = 0; pass < 4; ++pass) {
    const int hm = pass >> 1, hn = pass & 1;
    __syncthreads();
    if (wm == hm && wn == hn) {
      #pragma unroll
      for (int mf = 0; mf < 4; ++mf)
        #pragma unroll
        for (int nf = 0; nf < 2; ++nf)
          #pragma unroll
          for (int qv = 0; qv < 4; ++qv)
            *(f32x4_t*)&eps[(nf*32 + l31)*132 + mf*32 + qv*8 + 4*hi] =
                (f32x4_t){acc[mf][nf][qv*4+0], acc[mf][nf][qv*4+1],
                          acc[mf][nf][qv*4+2], acc[mf][nf][qv*4+3]};
    }
    __syncthreads();
    const int i = i0 + hm*2 + (q >> 1);
    if (i < 190) {
      float* dst = outb + (size_t)(oc0 + hn*64 + ocr)*36100u + i*190 + j0 + (q&1)*32;
      const float* src = eps + ocr*132 + q*32;
      const int kmax = (ct == 2 && (q & 1)) ? 30 : 32;
      for (int k = 0; k < kmax; k += 2)
        *(float2*)(dst + k) = make_float2(src[k], src[k + 1]);
    }
  }
}

extern "C" void kernel_launch(void* const* d_in, const int* in_sizes, int n_in,
                              void* d_out, int out_size, void* d_ws, size_t ws_size,
                              hipStream_t stream)
{
  const float* x = (const float*)d_in[0];
  const float* w = (const float*)d_in[1];
  float* out = (float*)d_out;

  char* ws = (char*)d_ws;
  float*          xT = (float*)ws;                         // 8,388,608 B
  __hip_bfloat16* wb = (__hip_bfloat16*)(ws + 8388608);    // 1,179,648 B
  __hip_bfloat16* xo = (__hip_bfloat16*)(ws + 9568256);    // 5 or 1 x 37,748,736 B

  const bool merged = (ws_size >= 198311936ull);

  k_transpose<<<dim3(64, 64, 2), 256, 0, stream>>>(x, xT);
  k_wconv<<<2304, 256, 0, stream>>>(w, wb);

  if (merged) {
    k_sample<<<dim3(48, 192, 5), 256, 0, stream>>>(xT, xo, 0);
    k_conv8<<<dim3(6, 48, 10), 256, 0, stream>>>(xo, wb, out);
  } else {
    for (int aidx = 0; aidx < 5; ++aidx) {
      k_sample<<<dim3(48, 192, 1), 256, 0, stream>>>(xT, xo, aidx);
      k_conv8<<<dim3(6, 48, 2), 256, 0, stream>>>(xo, wb, out + (size_t)aidx * 18483200u);
    }
  }
}